// Round 2
// baseline (3851.031 us; speedup 1.0000x reference)
//
#include <hip/hip_runtime.h>
#include <float.h>
#include <math.h>

// ---------------------------------------------------------------------------
// Round 1: identical to Round 0 (container infra failure — never executed).
//   k_stats : RevIN mean/rstd/std per (b,v)
//   k_c2    : centroid squared norms
//   k_mlp   : per (b,v,d-quarter) block: xn -> encode(16->128) -> LN(D) ->
//             transpose -> fc1(64->256) relu -> fcm(256->512) relu ->
//             fc2(512->32) -> z_p[(b,v,f),d]   (fully LDS-fused, 64KB)
//   k_vq    : dist GEMM + logits + top5 + softmax + codebook gather +
//             fusion GEMM + LN + decode + RevIN denorm
// ws layout (floats): mean[2048] | rstd[2048] | std[2048] | pad->6144 c2[1024]
//                     | @8192 z_p[65536*128]  (~33.6 MB total)
// ---------------------------------------------------------------------------

__global__ __launch_bounds__(1024)
void k_stats(const float* __restrict__ x, float* __restrict__ stats) {
  __shared__ float s1[16][64];
  __shared__ float s2[16][64];
  const int v = threadIdx.x, seg = threadIdx.y, b = blockIdx.x;
  float a = 0.f, aa = 0.f;
  const float* xp = x + (b * 1024 + seg * 64) * 64 + v;
  for (int i = 0; i < 64; ++i) { const float t = xp[i * 64]; a += t; aa += t * t; }
  s1[seg][v] = a; s2[seg][v] = aa;
  __syncthreads();
  if (seg == 0) {
    float S = 0.f, SS = 0.f;
    for (int j = 0; j < 16; ++j) { S += s1[j][v]; SS += s2[j][v]; }
    const float mu  = S * (1.f / 1024.f);
    const float var = SS * (1.f / 1024.f) - mu * mu;
    const float sd  = sqrtf(var + 1e-5f);
    stats[b * 64 + v]        = mu;
    stats[2048 + b * 64 + v] = 1.f / sd;
    stats[4096 + b * 64 + v] = sd;
  }
}

__global__ __launch_bounds__(256)
void k_c2(const float* __restrict__ centroids, float* __restrict__ c2) {
  const int k = blockIdx.x * 256 + threadIdx.x;
  const float* cp = centroids + k * 128;
  float s = 0.f;
  for (int d = 0; d < 128; d += 4) {
    const float4 c = *(const float4*)(cp + d);
    s += c.x * c.x + c.y * c.y + c.z * c.z + c.w * c.w;
  }
  c2[k] = s;
}

// Fused encode + LN + MLP. Block = (b,v, d-quarter q): 32 MLP rows (d = q*32..+31).
// LDS regions (byte offsets into 64KB):
//   sz  @0      [64][128] f32 (A)      h1  @0      [32][260] (B,C)
//   h0  @33280  [32][68]  (A,B)        h2c @33280  [32][68]  (C)
//   wstg@41984  enc[16][128](A) / W1c[16][256](B) / Wmc[64][68](C)
//   red @59392  [64][8] (A)            zt  @59392  [32][33]  (D)
//   sxn @61440  [1024] (A)
__global__ __launch_bounds__(256)
void k_mlp(const float* __restrict__ x,
           const float* __restrict__ enc_w, const float* __restrict__ enc_b,
           const float* __restrict__ ln_w,  const float* __restrict__ ln_b,
           const float* __restrict__ fc1_w, const float* __restrict__ fc1_b,
           const float* __restrict__ fcm_w, const float* __restrict__ fcm_b,
           const float* __restrict__ fc2_w, const float* __restrict__ fc2_b,
           const float* __restrict__ stats, float* __restrict__ z_p) {
  __shared__ __align__(16) char smem[65536];
  float* sz   = (float*)(smem);
  float* h1   = (float*)(smem);
  float* h0   = (float*)(smem + 33280);
  float* h2c  = (float*)(smem + 33280);
  float* wstg = (float*)(smem + 41984);
  float* red  = (float*)(smem + 59392);
  float* zt   = (float*)(smem + 59392);
  float* sxn  = (float*)(smem + 61440);

  const int tid = threadIdx.x;
  const int bv  = blockIdx.x >> 2;
  const int q   = blockIdx.x & 3;
  const int b   = bv >> 6, v = bv & 63;

  // ---------------- Phase A: xn -> encode -> LN -> h0[d_local][p]
  {
    const float mn = stats[bv];
    const float rs = stats[2048 + bv];
    const float* xb = x + (b * 1024) * 64 + v;
    for (int i = tid; i < 1024; i += 256) sxn[i] = (xb[i * 64] - mn) * rs;
    for (int i = tid; i < 2048; i += 256) wstg[i] = enc_w[i];
    __syncthreads();

    const int p = tid >> 2, qd = tid & 3;
    float xr[16];
#pragma unroll
    for (int t = 0; t < 16; ++t) xr[t] = sxn[p * 16 + t];
    float s1 = 0.f, s2 = 0.f;
    for (int dl = 0; dl < 32; ++dl) {
      const int d = qd * 32 + dl;
      float z = enc_b[d];
#pragma unroll
      for (int t = 0; t < 16; ++t) z += xr[t] * wstg[t * 128 + d];
      sz[p * 128 + d] = z;
      s1 += z; s2 += z * z;
    }
    red[p * 8 + qd * 2]     = s1;
    red[p * 8 + qd * 2 + 1] = s2;
    __syncthreads();
    if (tid < 64) {
      const float S1 = red[tid*8+0] + red[tid*8+2] + red[tid*8+4] + red[tid*8+6];
      const float S2 = red[tid*8+1] + red[tid*8+3] + red[tid*8+5] + red[tid*8+7];
      const float mu  = S1 * (1.f / 128.f);
      const float var = S2 * (1.f / 128.f) - mu * mu;
      red[tid * 8]     = mu;
      red[tid * 8 + 1] = rsqrtf(var + 1e-5f);
    }
    __syncthreads();
    const int dl = tid >> 3, p0 = (tid & 7) * 8;
    const int d  = q * 32 + dl;
    const float lw = ln_w[d], lb = ln_b[d];
#pragma unroll
    for (int e = 0; e < 8; ++e) {
      const int pp = p0 + e;
      const float zz = sz[pp * 128 + d];
      h0[dl * 68 + pp] = (zz - red[pp * 8]) * red[pp * 8 + 1] * lw + lb;
    }
    __syncthreads();
  }

  // ---------------- Phase B: h1[32][260] = relu(h0 @ fc1_w + b1)
  {
    const int tr = tid >> 5;   // 8 row-groups of 4
    const int tc = tid & 31;   // 32 col-groups of 8
    float acc[4][8];
#pragma unroll
    for (int i = 0; i < 4; ++i)
#pragma unroll
      for (int j = 0; j < 8; ++j) acc[i][j] = 0.f;

    for (int kc = 0; kc < 4; ++kc) {
      for (int i = tid * 4; i < 4096; i += 1024)
        *(float4*)(wstg + i) = *(const float4*)(fc1_w + kc * 4096 + i);
      __syncthreads();
#pragma unroll
      for (int k4 = 0; k4 < 16; k4 += 4) {
        float4 a[4];
#pragma unroll
        for (int i = 0; i < 4; ++i)
          a[i] = *(float4*)(h0 + (4 * tr + i) * 68 + kc * 16 + k4);
#pragma unroll
        for (int kk = 0; kk < 4; ++kk) {
          const float4 b0 = *(float4*)(wstg + (k4 + kk) * 256 + 8 * tc);
          const float4 b1 = *(float4*)(wstg + (k4 + kk) * 256 + 8 * tc + 4);
#pragma unroll
          for (int i = 0; i < 4; ++i) {
            const float av = ((const float*)&a[i])[kk];
            acc[i][0] += av * b0.x; acc[i][1] += av * b0.y;
            acc[i][2] += av * b0.z; acc[i][3] += av * b0.w;
            acc[i][4] += av * b1.x; acc[i][5] += av * b1.y;
            acc[i][6] += av * b1.z; acc[i][7] += av * b1.w;
          }
        }
      }
      __syncthreads();
    }
    float bb[8];
#pragma unroll
    for (int j = 0; j < 8; ++j) bb[j] = fc1_b[8 * tc + j];
#pragma unroll
    for (int i = 0; i < 4; ++i)
#pragma unroll
      for (int j = 0; j < 8; ++j) {
        const float vv = acc[i][j] + bb[j];
        h1[(4 * tr + i) * 260 + 8 * tc + j] = vv > 0.f ? vv : 0.f;
      }
    __syncthreads();
  }

  // ---------------- Phase C: h2 col-chunks (relu(h1@Wm+bm)) feeding GEMM3 acc
  const int t2r = tid >> 4, t2c = tid & 15;          // GEMM2: rows 2t2r..+1, cols 4t2c..+3
  const int t3r = tid >> 3, t3c = tid & 7;           // GEMM3: row t3r, cols 4t3c..+3
  const int lkk = tid >> 2, lj0 = (tid & 3) * 16;    // Wmc coop-load
  float acc3[4];
#pragma unroll
  for (int j = 0; j < 4; ++j) acc3[j] = fc2_b[4 * t3c + j];

  for (int cc = 0; cc < 8; ++cc) {
    const int C0 = cc * 64;
    float acc2[2][4];
    {
      const float4 bm = *(const float4*)(fcm_b + C0 + 4 * t2c);
      acc2[0][0] = bm.x; acc2[0][1] = bm.y; acc2[0][2] = bm.z; acc2[0][3] = bm.w;
      acc2[1][0] = bm.x; acc2[1][1] = bm.y; acc2[1][2] = bm.z; acc2[1][3] = bm.w;
    }
    for (int k1c = 0; k1c < 4; ++k1c) {
      const int K0 = k1c * 64;
      __syncthreads();   // prev Wmc reads & prev-cc h2c reads complete
#pragma unroll
      for (int jj = 0; jj < 4; ++jj)
        *(float4*)(wstg + lkk * 68 + lj0 + 4 * jj) =
            *(const float4*)(fcm_w + (K0 + lkk) * 512 + C0 + lj0 + 4 * jj);
      __syncthreads();
      for (int k4 = 0; k4 < 64; k4 += 4) {
        const float4 a0 = *(float4*)(h1 + (2 * t2r) * 260 + K0 + k4);
        const float4 a1 = *(float4*)(h1 + (2 * t2r + 1) * 260 + K0 + k4);
#pragma unroll
        for (int kk = 0; kk < 4; ++kk) {
          const float4 bw = *(float4*)(wstg + (k4 + kk) * 68 + 4 * t2c);
          const float a0v = ((const float*)&a0)[kk];
          const float a1v = ((const float*)&a1)[kk];
          acc2[0][0] += a0v * bw.x; acc2[0][1] += a0v * bw.y;
          acc2[0][2] += a0v * bw.z; acc2[0][3] += a0v * bw.w;
          acc2[1][0] += a1v * bw.x; acc2[1][1] += a1v * bw.y;
          acc2[1][2] += a1v * bw.z; acc2[1][3] += a1v * bw.w;
        }
      }
    }
#pragma unroll
    for (int i = 0; i < 2; ++i) {
      float4 st;
      st.x = fmaxf(acc2[i][0], 0.f); st.y = fmaxf(acc2[i][1], 0.f);
      st.z = fmaxf(acc2[i][2], 0.f); st.w = fmaxf(acc2[i][3], 0.f);
      *(float4*)(h2c + (2 * t2r + i) * 68 + 4 * t2c) = st;
    }
    __syncthreads();
    for (int j4 = 0; j4 < 64; j4 += 4) {
      const float4 a = *(float4*)(h2c + t3r * 68 + j4);
#pragma unroll
      for (int jj = 0; jj < 4; ++jj) {
        const float4 bw = *(const float4*)(fc2_w + (C0 + j4 + jj) * 32 + 4 * t3c);
        const float av = ((const float*)&a)[jj];
        acc3[0] += av * bw.x; acc3[1] += av * bw.y;
        acc3[2] += av * bw.z; acc3[3] += av * bw.w;
      }
    }
  }
  __syncthreads();

  // ---------------- Phase D: transpose (rows d, cols f) -> z_p[(bv,f),d]
#pragma unroll
  for (int j = 0; j < 4; ++j) zt[(4 * t3c + j) * 33 + t3r] = acc3[j];
  __syncthreads();
  {
    const int f = tid >> 3, dl4 = (tid & 7) * 4;
    float4 o;
    o.x = zt[f * 33 + dl4 + 0];
    o.y = zt[f * 33 + dl4 + 1];
    o.z = zt[f * 33 + dl4 + 2];
    o.w = zt[f * 33 + dl4 + 3];
    *(float4*)(z_p + (bv * 32 + f) * 128 + q * 32 + dl4) = o;
  }
}

__device__ __forceinline__ void top5_insert(float dv, int ki, float* dd, int* ii) {
  if (dv < dd[4]) {
    dd[4] = dv; ii[4] = ki;
#pragma unroll
    for (int j = 4; j > 0; --j) {
      if (dd[j] < dd[j - 1]) {
        const float td = dd[j]; dd[j] = dd[j - 1]; dd[j - 1] = td;
        const int   ti = ii[j]; ii[j] = ii[j - 1]; ii[j - 1] = ti;
      }
    }
  }
}

// Block = one (b,v): rows f=0..31. dist GEMM + logits + top5 + softmax +
// gather + fusion + LN + decode + denorm.
__global__ __launch_bounds__(256)
void k_vq(const float* __restrict__ z_p, const float* __restrict__ centroids,
          const float* __restrict__ c2g,
          const float* __restrict__ fuse_w, const float* __restrict__ fuse_b,
          const float* __restrict__ fln_w,  const float* __restrict__ fln_b,
          const float* __restrict__ dec_w,  const float* __restrict__ dec_b,
          const float* __restrict__ stats,
          float* __restrict__ outputs, float* __restrict__ logits) {
  __shared__ __align__(16) char smem[52352];
  float* zr     = (float*)(smem);            // [32][132]
  float* ct     = (float*)(smem + 16896);    // [64][132] (dist phase)
  float* cand_d = (float*)(smem + 16896);    // [32][80]  (merge)
  int*   cand_i = (int*)  (smem + 27136);    // [32][80]
  float* zc     = (float*)(smem + 16896);    // [32][132] (post-merge)
  float* z2     = (float*)(smem + 50688);    // [32]
  float* wrow   = (float*)(smem + 50816);    // [32][5]
  int*   irow   = (int*)  (smem + 51456);    // [32][5]
  float* lnstat = (float*)(smem + 52096);    // [32][2]

  const int tid = threadIdx.x;
  const int bv  = blockIdx.x;
  const int b   = bv >> 6, v = bv & 63;

  for (int i = tid; i < 1024; i += 256) {
    const int r = i >> 5, c4 = (i & 31) * 4;
    *(float4*)(zr + r * 132 + c4) = *(const float4*)(z_p + (bv * 32 + r) * 128 + c4);
  }
  __syncthreads();
  if (tid < 32) {
    float s = 0.f;
    for (int d = 0; d < 128; ++d) { const float t = zr[tid * 132 + d]; s += t * t; }
    z2[tid] = s;
  }
  __syncthreads();

  const int tr = tid >> 4, tk = tid & 15;   // rows 2tr..+1, k-cols 4tk..+3 per tile
  float d5[2][5]; int i5[2][5];
#pragma unroll
  for (int i = 0; i < 2; ++i)
#pragma unroll
    for (int j = 0; j < 5; ++j) { d5[i][j] = FLT_MAX; i5[i][j] = 0x7fffffff; }

  for (int kt = 0; kt < 1024; kt += 64) {
    for (int i = tid; i < 2048; i += 256) {
      const int r = i >> 5, c4 = (i & 31) * 4;
      *(float4*)(ct + r * 132 + c4) = *(const float4*)(centroids + (kt + r) * 128 + c4);
    }
    __syncthreads();
    float dot[2][4];
#pragma unroll
    for (int i = 0; i < 2; ++i)
#pragma unroll
      for (int j = 0; j < 4; ++j) dot[i][j] = 0.f;
    for (int d4 = 0; d4 < 128; d4 += 4) {
      const float4 a0 = *(float4*)(zr + (2 * tr) * 132 + d4);
      const float4 a1 = *(float4*)(zr + (2 * tr + 1) * 132 + d4);
#pragma unroll
      for (int kk = 0; kk < 4; ++kk) {
        const float4 bb = *(float4*)(ct + (4 * tk + kk) * 132 + d4);
        dot[0][kk] += a0.x * bb.x + a0.y * bb.y + a0.z * bb.z + a0.w * bb.w;
        dot[1][kk] += a1.x * bb.x + a1.y * bb.y + a1.z * bb.z + a1.w * bb.w;
      }
    }
    const float zz0 = z2[2 * tr], zz1 = z2[2 * tr + 1];
    float l0[4], l1[4];
#pragma unroll
    for (int kk = 0; kk < 4; ++kk) {
      const int k = kt + 4 * tk + kk;
      const float cc2 = c2g[k];
      const float di0 = zz0 + cc2 - 2.f * dot[0][kk];
      const float di1 = zz1 + cc2 - 2.f * dot[1][kk];
      l0[kk] = -di0; l1[kk] = -di1;
      top5_insert(di0, k, d5[0], i5[0]);
      top5_insert(di1, k, d5[1], i5[1]);
    }
    *(float4*)(logits + (bv * 32 + 2 * tr) * 1024 + kt + 4 * tk) =
        make_float4(l0[0], l0[1], l0[2], l0[3]);
    *(float4*)(logits + (bv * 32 + 2 * tr + 1) * 1024 + kt + 4 * tk) =
        make_float4(l1[0], l1[1], l1[2], l1[3]);
    __syncthreads();
  }

  // merge 16 partial top-5 lists per row (tie-break: lowest k, matching lax.top_k)
#pragma unroll
  for (int i = 0; i < 2; ++i)
#pragma unroll
    for (int j = 0; j < 5; ++j) {
      cand_d[(2 * tr + i) * 80 + tk * 5 + j] = d5[i][j];
      cand_i[(2 * tr + i) * 80 + tk * 5 + j] = i5[i][j];
    }
  __syncthreads();
  if (tid < 32) {
    const int r = tid;
    float bd[5]; int bi[5];
    for (int s = 0; s < 5; ++s) {
      float best = FLT_MAX; int besti = 0x7fffffff; int bpos = 0;
      for (int c = 0; c < 80; ++c) {
        const float dv = cand_d[r * 80 + c]; const int ki = cand_i[r * 80 + c];
        if (dv < best || (dv == best && ki < besti)) { best = dv; besti = ki; bpos = c; }
      }
      bd[s] = best; bi[s] = besti;
      cand_d[r * 80 + bpos] = FLT_MAX;
    }
    float e[5]; float sum = 0.f;
    for (int j = 0; j < 5; ++j) { e[j] = expf(bd[0] - bd[j]); sum += e[j]; }
    const float inv = 1.f / sum;
    for (int j = 0; j < 5; ++j) { wrow[r * 5 + j] = e[j] * inv; irow[r * 5 + j] = bi[j]; }
  }
  __syncthreads();

  // z_code = sum_j w_j * centroids[idx_j]  -> zc
  {
    const int r = tid >> 3, d0 = (tid & 7) * 16;
    float acc[16];
#pragma unroll
    for (int dd = 0; dd < 16; ++dd) acc[dd] = 0.f;
    for (int j = 0; j < 5; ++j) {
      const float w = wrow[r * 5 + j];
      const int   k = irow[r * 5 + j];
      const float* cp = centroids + k * 128 + d0;
#pragma unroll
      for (int dd = 0; dd < 16; dd += 4) {
        const float4 cv = *(const float4*)(cp + dd);
        acc[dd]   += w * cv.x; acc[dd+1] += w * cv.y;
        acc[dd+2] += w * cv.z; acc[dd+3] += w * cv.w;
      }
    }
#pragma unroll
    for (int dd = 0; dd < 16; dd += 4)
      *(float4*)(zc + r * 132 + d0 + dd) =
          make_float4(acc[dd], acc[dd+1], acc[dd+2], acc[dd+3]);
  }
  __syncthreads();

  // zc += relu(zr @ fuse_w + fuse_b)
  {
    const int fr = tid >> 4, fcg = tid & 15;
    float g[2][8];
    {
      const float4 b0 = *(const float4*)(fuse_b + 8 * fcg);
      const float4 b1 = *(const float4*)(fuse_b + 8 * fcg + 4);
      g[0][0]=b0.x; g[0][1]=b0.y; g[0][2]=b0.z; g[0][3]=b0.w;
      g[0][4]=b1.x; g[0][5]=b1.y; g[0][6]=b1.z; g[0][7]=b1.w;
#pragma unroll
      for (int j = 0; j < 8; ++j) g[1][j] = g[0][j];
    }
    for (int d4 = 0; d4 < 128; d4 += 4) {
      const float4 a0 = *(float4*)(zr + (2 * fr) * 132 + d4);
      const float4 a1 = *(float4*)(zr + (2 * fr + 1) * 132 + d4);
#pragma unroll
      for (int dd = 0; dd < 4; ++dd) {
        const float* wp = fuse_w + (d4 + dd) * 128 + 8 * fcg;
        const float4 w0 = *(const float4*)(wp);
        const float4 w1 = *(const float4*)(wp + 4);
        const float a0v = ((const float*)&a0)[dd];
        const float a1v = ((const float*)&a1)[dd];
        g[0][0] += a0v*w0.x; g[0][1] += a0v*w0.y; g[0][2] += a0v*w0.z; g[0][3] += a0v*w0.w;
        g[0][4] += a0v*w1.x; g[0][5] += a0v*w1.y; g[0][6] += a0v*w1.z; g[0][7] += a0v*w1.w;
        g[1][0] += a1v*w0.x; g[1][1] += a1v*w0.y; g[1][2] += a1v*w0.z; g[1][3] += a1v*w0.w;
        g[1][4] += a1v*w1.x; g[1][5] += a1v*w1.y; g[1][6] += a1v*w1.z; g[1][7] += a1v*w1.w;
      }
    }
#pragma unroll
    for (int i = 0; i < 2; ++i)
#pragma unroll
      for (int j = 0; j < 8; ++j)
        zc[(2 * fr + i) * 132 + 8 * fcg + j] += fmaxf(g[i][j], 0.f);
  }
  __syncthreads();

  if (tid < 32) {
    float s = 0.f, ss = 0.f;
    for (int d = 0; d < 128; ++d) { const float t = zc[tid * 132 + d]; s += t; ss += t * t; }
    const float mu  = s * (1.f / 128.f);
    const float var = ss * (1.f / 128.f) - mu * mu;
    lnstat[tid * 2]     = mu;
    lnstat[tid * 2 + 1] = rsqrtf(var + 1e-5f);
  }
  __syncthreads();

  // decode (D->16) + unpatchify + RevIN denorm
  {
    const int r = tid >> 3, tt = (tid & 7) * 2;
    const float mu = lnstat[r * 2], rsd = lnstat[r * 2 + 1];
    float o0 = dec_b[tt], o1 = dec_b[tt + 1];
    for (int d = 0; d < 128; ++d) {
      const float zf = (zc[r * 132 + d] - mu) * rsd * fln_w[d] + fln_b[d];
      o0 += zf * dec_w[d * 16 + tt];
      o1 += zf * dec_w[d * 16 + tt + 1];
    }
    const float sd = stats[4096 + bv], mn = stats[bv];
    outputs[(b * 512 + r * 16 + tt) * 64 + v]     = o0 * sd + mn;
    outputs[(b * 512 + r * 16 + tt + 1) * 64 + v] = o1 * sd + mn;
  }
}

extern "C" void kernel_launch(void* const* d_in, const int* in_sizes, int n_in,
                              void* d_out, int out_size, void* d_ws, size_t ws_size,
                              hipStream_t stream) {
  const float* x      = (const float*)d_in[0];
  const float* cent   = (const float*)d_in[1];
  const float* enc_w  = (const float*)d_in[2];
  const float* enc_b  = (const float*)d_in[3];
  const float* ln_w   = (const float*)d_in[4];
  const float* ln_b   = (const float*)d_in[5];
  const float* fc1_w  = (const float*)d_in[6];
  const float* fc1_b  = (const float*)d_in[7];
  const float* fcm_w  = (const float*)d_in[8];
  const float* fcm_b  = (const float*)d_in[9];
  const float* fc2_w  = (const float*)d_in[10];
  const float* fc2_b  = (const float*)d_in[11];
  const float* fuse_w = (const float*)d_in[12];
  const float* fuse_b = (const float*)d_in[13];
  const float* fln_w  = (const float*)d_in[14];
  const float* fln_b  = (const float*)d_in[15];
  const float* dec_w  = (const float*)d_in[16];
  const float* dec_b  = (const float*)d_in[17];

  float* ws    = (float*)d_ws;
  float* stats = ws;            // mean[2048] rstd[2048] std[2048]
  float* c2    = ws + 6144;     // [1024]
  float* z_p   = ws + 8192;     // [65536][128]

  float* outputs = (float*)d_out;
  float* logits  = (float*)d_out + 32 * 512 * 64;

  k_stats<<<dim3(32), dim3(64, 16), 0, stream>>>(x, stats);
  k_c2<<<dim3(4), dim3(256), 0, stream>>>(cent, c2);
  k_mlp<<<dim3(8192), dim3(256), 0, stream>>>(x, enc_w, enc_b, ln_w, ln_b,
      fc1_w, fc1_b, fcm_w, fcm_b, fc2_w, fc2_b, stats, z_p);
  k_vq<<<dim3(2048), dim3(256), 0, stream>>>(z_p, cent, c2, fuse_w, fuse_b,
      fln_w, fln_b, dec_w, dec_b, stats, outputs, logits);
}